// Round 4
// baseline (211.381 us; speedup 1.0000x reference)
//
#include <hip/hip_runtime.h>

#define NUM_CLASSES 80
constexpr int Bn = 8;
constexpr int Gn = 128;
constexpr int An = 131072;

constexpr int TB   = 256;       // threads per block
constexpr int PH   = 2;         // sequential anchor phases per thread
constexpr int BBLK = TB * PH;   // 512 anchors per block

// out layout: cls (B,A,80) | reg (B,A,4) | states (B,A)
constexpr size_t CLS_OFF = 0;
constexpr size_t REG_OFF = (size_t)Bn * An * NUM_CLASSES;
constexpr size_t ST_OFF  = REG_OFF + (size_t)Bn * An * 4;

__global__ __launch_bounds__(TB, 8) void targets_kernel(
    const float* __restrict__ ann,      // (B,G,5) x1,y1,x2,y2,label
    const float* __restrict__ anchors,  // (A,4)
    float* __restrict__ out)
{
#pragma clang fp contract(off)
    const int tid  = threadIdx.x;
    const int b    = blockIdx.y;
    const int base = blockIdx.x * BBLK;

    __shared__ float4 sbox[Gn];
    __shared__ float  sarea[Gn];
    __shared__ float  slabel[Gn];
    __shared__ int    slab[PH][TB];   // double-buffered: no cross-phase race

    if (tid < Gn) {
        const float* p = ann + ((size_t)b * Gn + tid) * 5;
        const float x1 = p[0], y1 = p[1], x2 = p[2], y2 = p[3];
        sbox[tid]  = make_float4(x1, y1, x2, y2);
        sarea[tid] = (x2 - x1) * (y2 - y1);   // ref op order
        slabel[tid] = p[4];
    }

    // prefetch both phases' anchors (coalesced float4, in flight past barrier)
    float4 av[PH];
    #pragma unroll
    for (int p = 0; p < PH; ++p)
        av[p] = *reinterpret_cast<const float4*>(
                    anchors + (size_t)(base + p * TB + tid) * 4);

    __syncthreads();

    #pragma unroll
    for (int p = 0; p < PH; ++p) {
        const int a = base + p * TB + tid;
        const float ax1 = av[p].x, ay1 = av[p].y, ax2 = av[p].z, ay2 = av[p].w;
        const float wa = ax2 - ax1;
        const float ha = ay2 - ay1;
        const float area_a = wa * ha;         // == (ax2-ax1)*(ay2-ay1)

        float best = -1.0f;                   // IoU >= 0 -> g=0 wins first
        int   besti = 0;
        #pragma unroll 2
        for (int g = 0; g < Gn; ++g) {
            const float4 bv = sbox[g];        // broadcast ds_read_b128
            const float area_b = sarea[g];    // broadcast ds_read_b32
            float iw = fminf(ax2, bv.z) - fmaxf(ax1, bv.x);
            iw = fmaxf(iw, 0.0f);
            float ih = fminf(ay2, bv.w) - fmaxf(ay1, bv.y);
            ih = fmaxf(ih, 0.0f);
            const float inter = iw * ih;
            float uni = (area_a + area_b) - inter;  // ref: a + b - inter
            uni = fmaxf(uni, 1e-8f);
            const float iou = inter / uni;          // IEEE fp32 div
            if (iou > best) { best = iou; besti = g; }  // first-index ties
        }

        // states
        const float st = (best >= 0.5f) ? 1.0f : ((best < 0.4f) ? 0.0f : -1.0f);
        out[ST_OFF + (size_t)b * An + a] = st;

        // reg targets
        const float4 gt = sbox[besti];
        float4 rv;
        rv.x = ((gt.x - ax1) / wa) / 0.2f;
        rv.y = ((gt.y - ay1) / ha) / 0.2f;
        rv.z = ((gt.z - ax2) / wa) / 0.2f;
        rv.w = ((gt.w - ay2) / ha) / 0.2f;
        *reinterpret_cast<float4*>(out + REG_OFF + ((size_t)b * An + a) * 4) = rv;

        // cls one-hot: stage labels, then block-cooperative coalesced writes
        slab[p][tid] = (st == 1.0f) ? (int)slabel[besti] : -1;
        __syncthreads();

        float4* dst = reinterpret_cast<float4*>(
            out + CLS_OFF + ((size_t)b * An + base + p * TB) * NUM_CLASSES);
        #pragma unroll
        for (int i = 0; i < 20; ++i) {
            const int p4  = tid + i * TB;     // 0..5119 float4s
            const int anc = p4 / 20;          // 20 float4 per anchor
            const int c0  = (p4 - anc * 20) * 4;
            const int lab = slab[p][anc];
            float4 v;
            v.x = (c0     == lab) ? 1.0f : 0.0f;
            v.y = (c0 + 1 == lab) ? 1.0f : 0.0f;
            v.z = (c0 + 2 == lab) ? 1.0f : 0.0f;
            v.w = (c0 + 3 == lab) ? 1.0f : 0.0f;
            dst[p4] = v;
        }
    }
}

extern "C" void kernel_launch(void* const* d_in, const int* in_sizes, int n_in,
                              void* d_out, int out_size, void* d_ws, size_t ws_size,
                              hipStream_t stream) {
    const float* ann     = (const float*)d_in[0];   // (8,128,5)
    const float* anchors = (const float*)d_in[1];   // (131072,4)
    float* out = (float*)d_out;

    dim3 grid(An / BBLK, Bn, 1);   // 256 x 8 = 2048 blocks, 8 per CU
    dim3 block(TB, 1, 1);
    targets_kernel<<<grid, block, 0, stream>>>(ann, anchors, out);
}

// Round 5
// 113.741 us; speedup vs baseline: 1.8584x; 1.8584x over previous
//
#include <hip/hip_runtime.h>

#define NUM_CLASSES 80
constexpr int Bn = 8;
constexpr int Gn = 128;
constexpr int An = 131072;

constexpr int TB = 64;   // ONE wave per block: no barriers, natural stagger

// out layout: cls (B,A,80) | reg (B,A,4) | states (B,A)
constexpr size_t CLS_OFF = 0;
constexpr size_t REG_OFF = (size_t)Bn * An * NUM_CLASSES;
constexpr size_t ST_OFF  = REG_OFF + (size_t)Bn * An * 4;

__global__ __launch_bounds__(TB, 8) void targets_kernel(
    const float* __restrict__ ann,      // (B,G,5) x1,y1,x2,y2,label
    const float* __restrict__ anchors,  // (A,4)
    float* __restrict__ out)
{
#pragma clang fp contract(off)
    const int lane = threadIdx.x;       // 0..63
    const int b    = blockIdx.y;
    const int a0   = blockIdx.x * TB;   // first anchor of this wave
    const int a    = a0 + lane;

    // stage boxes in this wave's LDS slice (wave-coherent: no barrier needed)
    __shared__ float4 sbox[Gn];
    __shared__ float  sarea[Gn];
    __shared__ float  slabel[Gn];
    #pragma unroll
    for (int i = lane; i < Gn; i += TB) {
        const float* p = ann + ((size_t)b * Gn + i) * 5;
        const float x1 = p[0], y1 = p[1], x2 = p[2], y2 = p[3];
        sbox[i]   = make_float4(x1, y1, x2, y2);
        sarea[i]  = (x2 - x1) * (y2 - y1);   // ref op order
        slabel[i] = p[4];
    }
    // single-wave block: ds_write->ds_read ordering enforced by lgkmcnt

    const float4 av = *reinterpret_cast<const float4*>(anchors + (size_t)a * 4);
    const float ax1 = av.x, ay1 = av.y, ax2 = av.z, ay2 = av.w;
    const float wa = ax2 - ax1;
    const float ha = ay2 - ay1;
    const float area_a = wa * ha;           // == (ax2-ax1)*(ay2-ay1)

    float best = -1.0f;                     // IoU >= 0 -> g=0 wins first
    int   besti = 0;
    #pragma unroll 2
    for (int g = 0; g < Gn; ++g) {
        const float4 bv = sbox[g];          // broadcast ds_read_b128
        const float area_b = sarea[g];      // broadcast ds_read_b32
        float iw = fminf(ax2, bv.z) - fmaxf(ax1, bv.x);
        iw = fmaxf(iw, 0.0f);
        float ih = fminf(ay2, bv.w) - fmaxf(ay1, bv.y);
        ih = fmaxf(ih, 0.0f);
        const float inter = iw * ih;
        float uni = (area_a + area_b) - inter;   // ref: a + b - inter
        uni = fmaxf(uni, 1e-8f);
        const float iou = inter / uni;           // IEEE fp32 div
        if (iou > best) { best = iou; besti = g; }   // first-index ties
    }

    // states
    const float st = (best >= 0.5f) ? 1.0f : ((best < 0.4f) ? 0.0f : -1.0f);
    out[ST_OFF + (size_t)b * An + a] = st;

    // reg targets
    {
        const float4 gt = sbox[besti];
        float4 rv;
        rv.x = ((gt.x - ax1) / wa) / 0.2f;
        rv.y = ((gt.y - ay1) / ha) / 0.2f;
        rv.z = ((gt.z - ax2) / wa) / 0.2f;
        rv.w = ((gt.w - ay2) / ha) / 0.2f;
        *reinterpret_cast<float4*>(out + REG_OFF + ((size_t)b * An + a) * 4) = rv;
    }

    // cls one-hot, wave-cooperative (no barrier): this wave owns 64 anchors
    // -> 64*80 floats = 1280 contiguous float4s; label pulled from owning
    // lane via __shfl (wave-synchronous ds_bpermute).
    const int mylab = (st == 1.0f) ? (int)slabel[besti] : -1;

    float4* dst = reinterpret_cast<float4*>(
        out + CLS_OFF + ((size_t)b * An + a0) * NUM_CLASSES);
    #pragma unroll
    for (int i = 0; i < 20; ++i) {
        const int p4  = i * TB + lane;      // 0..1279
        const int anc = p4 / 20;            // local anchor 0..63 (magic-mul)
        const int c0  = (p4 - anc * 20) * 4;
        const int lab = __shfl(mylab, anc, 64);
        float4 v;
        v.x = (c0     == lab) ? 1.0f : 0.0f;
        v.y = (c0 + 1 == lab) ? 1.0f : 0.0f;
        v.z = (c0 + 2 == lab) ? 1.0f : 0.0f;
        v.w = (c0 + 3 == lab) ? 1.0f : 0.0f;
        dst[p4] = v;
    }
}

extern "C" void kernel_launch(void* const* d_in, const int* in_sizes, int n_in,
                              void* d_out, int out_size, void* d_ws, size_t ws_size,
                              hipStream_t stream) {
    const float* ann     = (const float*)d_in[0];   // (8,128,5)
    const float* anchors = (const float*)d_in[1];   // (131072,4)
    float* out = (float*)d_out;

    dim3 grid(An / TB, Bn, 1);   // 2048 x 8 = 16384 one-wave blocks
    dim3 block(TB, 1, 1);
    targets_kernel<<<grid, block, 0, stream>>>(ann, anchors, out);
}